// Round 17
// baseline (429.351 us; speedup 1.0000x reference)
//
#include <hip/hip_runtime.h>
#include <hip/hip_bf16.h>

typedef __bf16 bf16_t;
typedef __bf16 bf16x8 __attribute__((ext_vector_type(8)));
typedef __bf16 bf16x4 __attribute__((ext_vector_type(4)));
typedef float f32x4 __attribute__((ext_vector_type(4)));

#define B_   8
#define C_   512
#define HW_  1024
#define NPIX 8192

// ---- async global->LDS (16B per lane) ----
typedef __attribute__((address_space(3))) void lds_vp;
typedef const __attribute__((address_space(1))) void gbl_vp;
__device__ __forceinline__ void gload_lds16(const void* g, void* l) {
    __builtin_amdgcn_global_load_lds((gbl_vp*)g, (lds_vp*)l, 16, 0, 0);
}

// Stage a 128x64 bf16 tile into LDS with the conflict-free swizzle:
// LDS byte layout: row*128 + slot*16, slot = kg ^ (row&7)  (kg = k/8).
__device__ __forceinline__ void stage128x64_swz(const bf16_t* __restrict__ g,
                                                bf16_t* lds, int tid) {
    int w64 = tid & ~63;
#pragma unroll
    for (int s = 0; s < 4; ++s) {
        int u = s * 256 + tid;
        int row = u >> 3;
        int kg = (u & 7) ^ (row & 7);
        const bf16_t* src = g + (size_t)row * 512 + kg * 8;
        gload_lds16((const void*)src, (void*)(lds + (size_t)(s * 256 + w64) * 8));
    }
}

// ---- K1: x [B,C,HW] f32 -> xT [B*HW, C] bf16 ; + weight cvt (fused) ----
__global__ void k_transpose(const float* __restrict__ x, bf16_t* __restrict__ xT,
                            const float* __restrict__ Wq, const float* __restrict__ Wk,
                            bf16_t* __restrict__ wq, bf16_t* __restrict__ wk) {
    __shared__ bf16_t tile[64 * 65];
    int p0 = blockIdx.x * 64, c0 = blockIdx.y * 64, b = blockIdx.z;
    int t = threadIdx.x;
    int widx = ((blockIdx.z * 8 + blockIdx.y) * 16 + blockIdx.x) * 256 + t;
    wq[widx] = (bf16_t)Wq[widx];
    wk[widx] = (bf16_t)Wk[widx];
#pragma unroll
    for (int s = 0; s < 4; ++s) {
        int u = s * 256 + t;
        int cr = u >> 4, pc = (u & 15) * 4;
        float4 v = *(const float4*)&x[((size_t)(b * C_ + c0 + cr)) * HW_ + p0 + pc];
        tile[cr * 65 + pc + 0] = (bf16_t)v.x;
        tile[cr * 65 + pc + 1] = (bf16_t)v.y;
        tile[cr * 65 + pc + 2] = (bf16_t)v.z;
        tile[cr * 65 + pc + 3] = (bf16_t)v.w;
    }
    __syncthreads();
#pragma unroll
    for (int s = 0; s < 4; ++s) {
        int u = s * 256 + t;
        int pr = u >> 4, cc = (u & 15) * 4;
        bf16x4 o;
        o[0] = tile[(cc + 0) * 65 + pr];
        o[1] = tile[(cc + 1) * 65 + pr];
        o[2] = tile[(cc + 2) * 65 + pr];
        o[3] = tile[(cc + 3) * 65 + pr];
        *(bf16x4*)&xT[((size_t)(b * HW_ + p0 + pr)) * C_ + c0 + cc] = o;
    }
}

// ---- K2: q/k projection GEMM (128x128 tiles, swizzled LDS, XCD remap) ----
__launch_bounds__(256, 2)
__global__ void k_gemm_qk(const bf16_t* __restrict__ xT,
                          const bf16_t* __restrict__ wq, const bf16_t* __restrict__ wk,
                          const float* __restrict__ bq, const float* __restrict__ bk,
                          bf16_t* __restrict__ qo, bf16_t* __restrict__ ko) {
    __shared__ __align__(16) bf16_t As[128 * 64];
    __shared__ __align__(16) bf16_t Bs[128 * 64];
    int bid = blockIdx.x;
    int xcd = bid & 7, j = bid >> 3;
    int mtile = xcd * 8 + (j >> 3);
    int nt = j & 7;
    const bf16_t* wsel = (nt < 4) ? wq : wk;
    const float*  bsel = (nt < 4) ? bq : bk;
    bf16_t*       osel = (nt < 4) ? qo : ko;
    int nb = (nt & 3) * 128;
    int i0 = mtile * 128;
    int tid = threadIdx.x;
    int lane = tid & 63, w = tid >> 6;
    int wr = w >> 1, wc = w & 1, lr = lane & 15, lg = lane >> 4;
    int kswz = (lg ^ (lr & 7)) << 4;

    f32x4 acc[4][4];
#pragma unroll
    for (int mi = 0; mi < 4; ++mi)
#pragma unroll
        for (int ni = 0; ni < 4; ++ni)
#pragma unroll
            for (int r = 0; r < 4; ++r) acc[mi][ni][r] = 0.f;

    for (int kt = 0; kt < 8; ++kt) {
        int k0 = kt * 64;
        stage128x64_swz(xT + (size_t)i0 * 512 + k0, As, tid);
        stage128x64_swz(wsel + (size_t)nb * 512 + k0, Bs, tid);
        asm volatile("s_waitcnt vmcnt(0)" ::: "memory");
        __builtin_amdgcn_s_barrier();
#pragma unroll
        for (int kk = 0; kk < 2; ++kk) {
            bf16x8 af[4], bfr[4];
#pragma unroll
            for (int mi = 0; mi < 4; ++mi)
                af[mi] = *(const bf16x8*)((const char*)As +
                    (wr * 64 + mi * 16 + lr) * 128 + (kswz ^ (kk * 64)));
#pragma unroll
            for (int ni = 0; ni < 4; ++ni)
                bfr[ni] = *(const bf16x8*)((const char*)Bs +
                    (wc * 64 + ni * 16 + lr) * 128 + (kswz ^ (kk * 64)));
#pragma unroll
            for (int mi = 0; mi < 4; ++mi)
#pragma unroll
                for (int ni = 0; ni < 4; ++ni)
                    acc[mi][ni] = __builtin_amdgcn_mfma_f32_16x16x32_bf16(
                        af[mi], bfr[ni], acc[mi][ni], 0, 0, 0);
        }
        __builtin_amdgcn_s_barrier();
    }
#pragma unroll
    for (int ni = 0; ni < 4; ++ni) {
        int col = nb + wc * 64 + ni * 16 + lr;
        float bias = bsel[col];
#pragma unroll
        for (int mi = 0; mi < 4; ++mi) {
            int rowb = i0 + wr * 64 + mi * 16 + lg * 4;
#pragma unroll
            for (int r = 0; r < 4; ++r)
                osel[(size_t)(rowb + r) * 512 + col] = (bf16_t)(acc[mi][ni][r] + bias);
        }
    }
}

// ---- K3: score GEMM + per-key-image max, wide-N (256x512 block tile) ----
// 256 blocks = (q-panel 256 rows) x (key image). 2 n-chunks x 8 K-tiles = 16.
// Wave tile 128x128 (2x4 wave grid): LDS reads/FLOP down 33% vs 128x64.
// LDS 96 KiB single-buffered: A[kh]=[256r][32k] @ kh*16384 (32KB);
// B[kh]=[512r][32k] @ 32768+kh*32768 (64KB).
// Swizzle (64B rows, 4 slots of 16B): phys slot = kg ^ ((row>>1)&3);
// read slot = lg ^ ((lr>>1)&3) -> 2 lanes/slot free (R15: 0 conflicts).
// Rolling ledger (tile T, phases P1..P4 = (k0,m0)(k0,m1)(k1,m0)(k1,m1)):
//   P1: stage A[k1](T)            (WAR: A[k1](T-1) last read P4(T-1))
//   P2: stage B[k0](T+1); vmcnt(4) forces A[k1](T)+B[k1](T) for P3
//   P3: stage A[k0](T+1)          (WAR: A[k0](T) last read-issue P2)
//   P4: stage B[k1](T+1); vmcnt(4) forces A[k0]+B[k0](T+1) for P1(T+1)
// (in-flight at each gate = 10, oldest 6 forced; verified by induction)

#define STAGE_A(KH, T)                                                             \
    gload_lds16((const void*)(q + srcA + ((T) & 7) * 64 + (KH) * 32),              \
                (void*)(ldsb + (KH) * 16384 + ldst));                              \
    gload_lds16((const void*)(q + srcA + (size_t)128 * 512 + ((T) & 7) * 64 +      \
                              (KH) * 32),                                          \
                (void*)(ldsb + (KH) * 16384 + 8192 + ldst));

#define STAGE_B(KH, T)                                                             \
    gload_lds16((const void*)(kb + srcB + (size_t)(((T) >> 3) * 512) * 512 +       \
                              ((T) & 7) * 64 + (KH) * 32),                         \
                (void*)(ldsb + 32768 + (KH) * 32768 + ldst));                      \
    gload_lds16((const void*)(kb + srcB + (size_t)(((T) >> 3) * 512 + 128) * 512 + \
                              ((T) & 7) * 64 + (KH) * 32),                         \
                (void*)(ldsb + 32768 + (KH) * 32768 + 8192 + ldst));               \
    gload_lds16((const void*)(kb + srcB + (size_t)(((T) >> 3) * 512 + 256) * 512 + \
                              ((T) & 7) * 64 + (KH) * 32),                         \
                (void*)(ldsb + 32768 + (KH) * 32768 + 16384 + ldst));              \
    gload_lds16((const void*)(kb + srcB + (size_t)(((T) >> 3) * 512 + 384) * 512 + \
                              ((T) & 7) * 64 + (KH) * 32),                         \
                (void*)(ldsb + 32768 + (KH) * 32768 + 24576 + ldst));

#define PHASE(KH, MH, STG, VM)                                                     \
    {                                                                              \
        const char* Ab = ldsb + (KH) * 16384;                                      \
        _Pragma("unroll")                                                          \
        for (int mi = 0; mi < 4; ++mi)                                             \
            af[mi] = *(const bf16x8*)(Ab + aoff + ((MH) * 4 + mi) * 1024);         \
        if ((MH) == 0) {                                                           \
            const char* Bb = ldsb + 32768 + (KH) * 32768;                          \
            _Pragma("unroll")                                                      \
            for (int n = 0; n < 8; ++n)                                            \
                bf[n] = *(const bf16x8*)(Bb + boff + n * 1024);                    \
        }                                                                          \
        STG;                                                                       \
        __builtin_amdgcn_s_setprio(1);                                             \
        _Pragma("unroll")                                                          \
        for (int mi = 0; mi < 4; ++mi)                                             \
            _Pragma("unroll")                                                      \
            for (int n = 0; n < 8; ++n)                                            \
                acc[(MH) * 4 + mi][n] = __builtin_amdgcn_mfma_f32_16x16x32_bf16(   \
                    af[mi], bf[n], acc[(MH) * 4 + mi][n], 0, 0, 0);                \
        __builtin_amdgcn_s_setprio(0);                                             \
        VM;                                                                        \
        __builtin_amdgcn_s_barrier();                                              \
    }

__global__ __launch_bounds__(512, 1)
void k_gemm_max8(const bf16_t* __restrict__ q, const bf16_t* __restrict__ kp,
                 float* __restrict__ Mout) {
    __shared__ __align__(16) bf16_t lds[49152];   // 96 KiB
    char* ldsb = (char*)lds;
    int bid = blockIdx.x;           // 256 blocks
    int img = bid & 7;              // XCD-local key image
    int qp = bid >> 3;              // 0..31
    int i0 = qp * 256;
    const bf16_t* kb = kp + (size_t)img * HW_ * C_;
    int tid = threadIdx.x;
    int lane = tid & 63, w = tid >> 6;
    int wr = w >> 2, wc = w & 3;    // 2 x 4 wave grid; wave tile 128x128
    int lr = lane & 15, lg = lane >> 4;
    int kswz = (lg ^ ((lr >> 1) & 3)) << 4;
    int aoff = (wr * 128 + lr) * 64 + kswz;
    int boff = (wc * 128 + lr) * 64 + kswz;

    // staging: thread t writes region bytes [t*16, t*16+16) per 8KB pass;
    // row = pass*128 + (t>>2), phys slot = t&3 -> kg = (t&3)^((t>>3)&3)
    int kg = (tid & 3) ^ ((tid >> 3) & 3);
    size_t srcA = (size_t)(i0 + (tid >> 2)) * 512 + kg * 8;
    size_t srcB = (size_t)(tid >> 2) * 512 + kg * 8;
    int ldst = (tid & ~63) * 16;    // wave-uniform LDS byte base

    f32x4 acc[8][8];
    bf16x8 af[4], bf[8];
    float rm[8][4];
#pragma unroll
    for (int mi = 0; mi < 8; ++mi)
#pragma unroll
        for (int n = 0; n < 8; ++n)
#pragma unroll
            for (int r = 0; r < 4; ++r) acc[mi][n][r] = 0.f;
#pragma unroll
    for (int mi = 0; mi < 8; ++mi)
#pragma unroll
        for (int r = 0; r < 4; ++r) rm[mi][r] = -3.4e38f;

    // prologue: B[k0](0) 4, A[k0](0) 2, B[k1](0) 4 -> vmcnt(4) forces B0+A0
    STAGE_B(0, 0)
    STAGE_A(0, 0)
    STAGE_B(1, 0)
    asm volatile("s_waitcnt vmcnt(4)" ::: "memory");
    __builtin_amdgcn_s_barrier();

    for (int T = 0; T < 16; ++T) {
        bool s = (T < 15);
        int Tn = T + 1;
        PHASE(0, 0, { STAGE_A(1, T) }, {})
        PHASE(0, 1, { if (s) { STAGE_B(0, Tn) } },
              { if (s) { asm volatile("s_waitcnt vmcnt(4)" ::: "memory"); }
                else   { asm volatile("s_waitcnt vmcnt(0)" ::: "memory"); } })
        PHASE(1, 0, { if (s) { STAGE_A(0, Tn) } }, {})
        PHASE(1, 1, { if (s) { STAGE_B(1, Tn) } },
              { if (s) { asm volatile("s_waitcnt vmcnt(4)" ::: "memory"); } })
        if ((T & 7) == 7) {   // n-chunk complete: fold acc into rm, reset acc
#pragma unroll
            for (int mi = 0; mi < 8; ++mi)
#pragma unroll
                for (int r = 0; r < 4; ++r) {
                    float v = fmaxf(fmaxf(fmaxf(acc[mi][0][r], acc[mi][1][r]),
                                          fmaxf(acc[mi][2][r], acc[mi][3][r])),
                                    fmaxf(fmaxf(acc[mi][4][r], acc[mi][5][r]),
                                          fmaxf(acc[mi][6][r], acc[mi][7][r])));
                    rm[mi][r] = fmaxf(rm[mi][r], v);
#pragma unroll
                    for (int n = 0; n < 8; ++n) acc[mi][n][r] = 0.f;
                }
        }
    }

    // epilogue: reduce across 16 col-lanes, then across the 4 wc waves
#pragma unroll
    for (int mi = 0; mi < 8; ++mi)
#pragma unroll
        for (int r = 0; r < 4; ++r) {
            float v = rm[mi][r];
#pragma unroll
            for (int off = 1; off < 16; off <<= 1) v = fmaxf(v, __shfl_xor(v, off));
            rm[mi][r] = v;
        }
    float* sm = (float*)lds;
    if (lr == 0) {
#pragma unroll
        for (int mi = 0; mi < 8; ++mi)
#pragma unroll
            for (int r = 0; r < 4; ++r)
                sm[wc * 256 + wr * 128 + mi * 16 + lg * 4 + r] = rm[mi][r];
    }
    __syncthreads();
    if (tid < 256) {
        float v = fmaxf(fmaxf(sm[tid], sm[256 + tid]),
                        fmaxf(sm[512 + tid], sm[768 + tid]));
        Mout[(size_t)(i0 + tid) * 8 + img] = v;
    }
}

// ---- K4: mean over key images, scale, softmax per query image ----
__global__ void k_softmax(const float* __restrict__ Mout, float* __restrict__ wsm) {
    int b = blockIdx.x;
    int t = threadIdx.x;
    __shared__ float red[16];
    const float scale = 0.044194173824159216f;  // 1/sqrt(512)
    float s[4];
#pragma unroll
    for (int i = 0; i < 4; ++i) {
        int p = t + i * 256;
        const float4* row = (const float4*)&Mout[(size_t)(b * 1024 + p) * 8];
        float4 r0 = row[0], r1 = row[1];
        float acc = (r0.x + r0.y + r0.z + r0.w) + (r1.x + r1.y + r1.z + r1.w);
        s[i] = acc * (scale / 8.0f);
    }
    float m = fmaxf(fmaxf(s[0], s[1]), fmaxf(s[2], s[3]));
#pragma unroll
    for (int off = 1; off < 64; off <<= 1) m = fmaxf(m, __shfl_xor(m, off));
    if ((t & 63) == 0) red[t >> 6] = m;
    __syncthreads();
    float m4 = fmaxf(fmaxf(red[0], red[1]), fmaxf(red[2], red[3]));
    float e[4], sum = 0.f;
#pragma unroll
    for (int i = 0; i < 4; ++i) { e[i] = __expf(s[i] - m4); sum += e[i]; }
#pragma unroll
    for (int off = 1; off < 64; off <<= 1) sum += __shfl_xor(sum, off);
    if ((t & 63) == 0) red[8 + (t >> 6)] = sum;
    __syncthreads();
    float tot = red[8] + red[9] + red[10] + red[11];
    float inv = 1.0f / tot;
#pragma unroll
    for (int i = 0; i < 4; ++i) wsm[b * 1024 + t + i * 256] = e[i] * inv;
}

// ---- K5: y[c] = mean_{b,p} x[b,c,p] * w[b,p]  (float4 loads) ----
__global__ void k_reduce_y(const float* __restrict__ x, const float* __restrict__ wsm,
                           float* __restrict__ y) {
    int c = blockIdx.x;
    int t = threadIdx.x;
    float acc = 0.f;
#pragma unroll
    for (int b = 0; b < 8; ++b) {
        float4 xv = ((const float4*)(x + ((size_t)(b * C_ + c)) * HW_))[t];
        float4 wv = ((const float4*)(wsm + b * HW_))[t];
        acc += xv.x * wv.x + xv.y * wv.y + xv.z * wv.z + xv.w * wv.w;
    }
#pragma unroll
    for (int off = 1; off < 64; off <<= 1) acc += __shfl_xor(acc, off);
    __shared__ float red[4];
    if ((t & 63) == 0) red[t >> 6] = acc;
    __syncthreads();
    if (t == 0) y[c] = (red[0] + red[1] + red[2] + red[3]) * (1.0f / 8192.0f);
}

// ---- K6: out = x * proto[c], proto computed in-block (fused k_proto) ----
__global__ void k_final(const float* __restrict__ x, const float* __restrict__ W6,
                        const float* __restrict__ b6, const float* __restrict__ y,
                        float* __restrict__ out) {
    int bid = blockIdx.x;           // 4096 = B_*C_
    int t = threadIdx.x;
    int c = bid & 511;
    float a = W6[(size_t)c * C_ + t] * y[t] +
              W6[(size_t)c * C_ + t + 256] * y[t + 256];
#pragma unroll
    for (int off = 1; off < 64; off <<= 1) a += __shfl_xor(a, off);
    __shared__ float red[4];
    if ((t & 63) == 0) red[t >> 6] = a;
    __syncthreads();
    float p = red[0] + red[1] + red[2] + red[3] + b6[c];
    int idx = bid * 256 + t;
    float4 v = ((const float4*)x)[idx];
    v.x *= p; v.y *= p; v.z *= p; v.w *= p;
    ((float4*)out)[idx] = v;
}

extern "C" void kernel_launch(void* const* d_in, const int* in_sizes, int n_in,
                              void* d_out, int out_size, void* d_ws, size_t ws_size,
                              hipStream_t stream) {
    const float* x  = (const float*)d_in[0];
    const float* Wq = (const float*)d_in[1];
    const float* bq = (const float*)d_in[2];
    const float* Wk = (const float*)d_in[3];
    const float* bk = (const float*)d_in[4];
    const float* W6 = (const float*)d_in[5];
    const float* b6 = (const float*)d_in[6];
    float* out = (float*)d_out;

    char* ws = (char*)d_ws;
    bf16_t* xT    = (bf16_t*)(ws);                 // 8.4 MB (dead after k_gemm_qk)
    float*  Mout  = (float*)(ws);                  // 8192*8*4 = 256 KB, aliases xT
    bf16_t* wqb   = (bf16_t*)(ws + 8388608);
    bf16_t* wkb   = (bf16_t*)(ws + 8912896);
    bf16_t* qb    = (bf16_t*)(ws + 9437184);
    bf16_t* kb    = (bf16_t*)(ws + 17825792);
    float*  wsm   = (float*)(ws + 26476544);
    float*  yv    = (float*)(ws + 26509312);

    hipLaunchKernelGGL(k_transpose, dim3(16, 8, 8), dim3(256), 0, stream,
                       x, xT, Wq, Wk, wqb, wkb);
    hipLaunchKernelGGL(k_gemm_qk, dim3(512), dim3(256), 0, stream,
                       xT, wqb, wkb, bq, bk, qb, kb);
    hipLaunchKernelGGL(k_gemm_max8, dim3(256), dim3(512), 0, stream, qb, kb, Mout);
    hipLaunchKernelGGL(k_softmax, dim3(8), dim3(256), 0, stream, Mout, wsm);
    hipLaunchKernelGGL(k_reduce_y, dim3(512), dim3(256), 0, stream, x, wsm, yv);
    hipLaunchKernelGGL(k_final, dim3(4096), dim3(256), 0, stream, x, W6, b6, yv, out);
}

// Round 18
// 93.833 us; speedup vs baseline: 4.5757x; 4.5757x over previous
//
#include <hip/hip_runtime.h>
#include <hip/hip_bf16.h>

typedef __bf16 bf16_t;
typedef __bf16 bf16x8 __attribute__((ext_vector_type(8)));
typedef __bf16 bf16x4 __attribute__((ext_vector_type(4)));
typedef float f32x4 __attribute__((ext_vector_type(4)));

#define B_   8
#define C_   512
#define HW_  1024
#define NPIX 8192

// ---- async global->LDS (16B per lane) ----
typedef __attribute__((address_space(3))) void lds_vp;
typedef const __attribute__((address_space(1))) void gbl_vp;
__device__ __forceinline__ void gload_lds16(const void* g, void* l) {
    __builtin_amdgcn_global_load_lds((gbl_vp*)g, (lds_vp*)l, 16, 0, 0);
}

// Stage a 128x64 bf16 tile into LDS with the conflict-free swizzle:
// LDS byte layout: row*128 + slot*16, slot = kg ^ (row&7)  (kg = k/8).
__device__ __forceinline__ void stage128x64_swz(const bf16_t* __restrict__ g,
                                                bf16_t* lds, int tid) {
    int w64 = tid & ~63;
#pragma unroll
    for (int s = 0; s < 4; ++s) {
        int u = s * 256 + tid;
        int row = u >> 3;
        int kg = (u & 7) ^ (row & 7);
        const bf16_t* src = g + (size_t)row * 512 + kg * 8;
        gload_lds16((const void*)src, (void*)(lds + (size_t)(s * 256 + w64) * 8));
    }
}

// ---- K1: x [B,C,HW] f32 -> xT [B*HW, C] bf16 ; + weight cvt (fused) ----
__global__ void k_transpose(const float* __restrict__ x, bf16_t* __restrict__ xT,
                            const float* __restrict__ Wq, const float* __restrict__ Wk,
                            bf16_t* __restrict__ wq, bf16_t* __restrict__ wk) {
    __shared__ bf16_t tile[64 * 65];
    int p0 = blockIdx.x * 64, c0 = blockIdx.y * 64, b = blockIdx.z;
    int t = threadIdx.x;
    int widx = ((blockIdx.z * 8 + blockIdx.y) * 16 + blockIdx.x) * 256 + t;
    wq[widx] = (bf16_t)Wq[widx];
    wk[widx] = (bf16_t)Wk[widx];
#pragma unroll
    for (int s = 0; s < 4; ++s) {
        int u = s * 256 + t;
        int cr = u >> 4, pc = (u & 15) * 4;
        float4 v = *(const float4*)&x[((size_t)(b * C_ + c0 + cr)) * HW_ + p0 + pc];
        tile[cr * 65 + pc + 0] = (bf16_t)v.x;
        tile[cr * 65 + pc + 1] = (bf16_t)v.y;
        tile[cr * 65 + pc + 2] = (bf16_t)v.z;
        tile[cr * 65 + pc + 3] = (bf16_t)v.w;
    }
    __syncthreads();
#pragma unroll
    for (int s = 0; s < 4; ++s) {
        int u = s * 256 + t;
        int pr = u >> 4, cc = (u & 15) * 4;
        bf16x4 o;
        o[0] = tile[(cc + 0) * 65 + pr];
        o[1] = tile[(cc + 1) * 65 + pr];
        o[2] = tile[(cc + 2) * 65 + pr];
        o[3] = tile[(cc + 3) * 65 + pr];
        *(bf16x4*)&xT[((size_t)(b * HW_ + p0 + pr)) * C_ + c0 + cc] = o;
    }
}

// ---- K2: q/k projection GEMM (128x128 tiles, swizzled LDS) ----
// XCD-aware remap: x = bid&7 (XCD), j = bid>>3; mtile = x*8 + (j>>3),
// nt = j&7 -> each XCD owns 8 contiguous A panels (1 MB, L2-resident)
// for all 8 output-column tiles. Bijective on 512 blocks.
__launch_bounds__(256, 2)
__global__ void k_gemm_qk(const bf16_t* __restrict__ xT,
                          const bf16_t* __restrict__ wq, const bf16_t* __restrict__ wk,
                          const float* __restrict__ bq, const float* __restrict__ bk,
                          bf16_t* __restrict__ qo, bf16_t* __restrict__ ko) {
    __shared__ __align__(16) bf16_t As[128 * 64];
    __shared__ __align__(16) bf16_t Bs[128 * 64];
    int bid = blockIdx.x;
    int xcd = bid & 7, j = bid >> 3;
    int mtile = xcd * 8 + (j >> 3);
    int nt = j & 7;
    const bf16_t* wsel = (nt < 4) ? wq : wk;
    const float*  bsel = (nt < 4) ? bq : bk;
    bf16_t*       osel = (nt < 4) ? qo : ko;
    int nb = (nt & 3) * 128;
    int i0 = mtile * 128;
    int tid = threadIdx.x;
    int lane = tid & 63, w = tid >> 6;
    int wr = w >> 1, wc = w & 1, lr = lane & 15, lg = lane >> 4;
    int kswz = (lg ^ (lr & 7)) << 4;

    f32x4 acc[4][4];
#pragma unroll
    for (int mi = 0; mi < 4; ++mi)
#pragma unroll
        for (int ni = 0; ni < 4; ++ni)
#pragma unroll
            for (int r = 0; r < 4; ++r) acc[mi][ni][r] = 0.f;

    for (int kt = 0; kt < 8; ++kt) {
        int k0 = kt * 64;
        stage128x64_swz(xT + (size_t)i0 * 512 + k0, As, tid);
        stage128x64_swz(wsel + (size_t)nb * 512 + k0, Bs, tid);
        asm volatile("s_waitcnt vmcnt(0)" ::: "memory");
        __builtin_amdgcn_s_barrier();
#pragma unroll
        for (int kk = 0; kk < 2; ++kk) {
            bf16x8 af[4], bfr[4];
#pragma unroll
            for (int mi = 0; mi < 4; ++mi)
                af[mi] = *(const bf16x8*)((const char*)As +
                    (wr * 64 + mi * 16 + lr) * 128 + (kswz ^ (kk * 64)));
#pragma unroll
            for (int ni = 0; ni < 4; ++ni)
                bfr[ni] = *(const bf16x8*)((const char*)Bs +
                    (wc * 64 + ni * 16 + lr) * 128 + (kswz ^ (kk * 64)));
#pragma unroll
            for (int mi = 0; mi < 4; ++mi)
#pragma unroll
                for (int ni = 0; ni < 4; ++ni)
                    acc[mi][ni] = __builtin_amdgcn_mfma_f32_16x16x32_bf16(
                        af[mi], bfr[ni], acc[mi][ni], 0, 0, 0);
        }
        __builtin_amdgcn_s_barrier();
    }
#pragma unroll
    for (int ni = 0; ni < 4; ++ni) {
        int col = nb + wc * 64 + ni * 16 + lr;
        float bias = bsel[col];
#pragma unroll
        for (int mi = 0; mi < 4; ++mi) {
            int rowb = i0 + wr * 64 + mi * 16 + lg * 4;
#pragma unroll
            for (int r = 0; r < 4; ++r)
                osel[(size_t)(rowb + r) * 512 + col] = (bf16_t)(acc[mi][ni][r] + bias);
        }
    }
}

// ---- K3: score GEMM + per-key-image max (proven: 66 us, 0 conflicts) ----
// 256 blocks = (q-panel 256 rows) x (key image). 32 K-tiles (4 n-chunks x 8).
// 8 LDS regions [128 rows][128 B]; swizzle byte-in-row ^= (row&7)<<4;
// read slot = (kh*4+lg) ^ (lr&7). Stage ledger:
//   ph1:A0d1(tb) ph2:B1d1(tb) ph3:A1d1(tb) ph4:B0d0(tc)+vmcnt(2)
//   ph5:A0d0(tc) ph6:B1d0(tc) ph7:A1d0(tc) ph8:B0d1(td)+vmcnt(2)

#define STAGE_A(RH, D, T)                                                          \
    gload_lds16((const void*)(q + srcA + (size_t)((RH) * 128) * 512 +              \
                              ((T) & 7) * 64),                                     \
                (void*)(ldsb + (RH) * 32768 + (D) * 16384 + ldw));                 \
    gload_lds16((const void*)(q + srcA + (size_t)((RH) * 128 + 64) * 512 +         \
                              ((T) & 7) * 64),                                     \
                (void*)(ldsb + (RH) * 32768 + (D) * 16384 + 8192 + ldw));

#define STAGE_B(RH, D, T)                                                          \
    gload_lds16((const void*)(kb + srcB +                                          \
                              (size_t)(((T) >> 3) * 256 + (RH) * 128) * 512 +      \
                              ((T) & 7) * 64),                                     \
                (void*)(ldsb + 65536 + (RH) * 32768 + (D) * 16384 + ldw));         \
    gload_lds16((const void*)(kb + srcB +                                          \
                              (size_t)(((T) >> 3) * 256 + (RH) * 128 + 64) * 512 + \
                              ((T) & 7) * 64),                                     \
                (void*)(ldsb + 65536 + (RH) * 32768 + (D) * 16384 + 8192 + ldw));

#define PHASE(D, KH, MH, STAGE_STMT, VM_STMT)                                      \
    {                                                                              \
        const char* Ab = ldsb + wr * 32768 + (D) * 16384;                          \
        const char* Bb = ldsb + 65536 + (wc >> 1) * 32768 + (D) * 16384;           \
        _Pragma("unroll")                                                          \
        for (int mi = 0; mi < 4; ++mi)                                             \
            af[mi] = *(const bf16x8*)(Ab + (aswz ^ ((KH) * 64)) +                  \
                                      ((MH) * 4 + mi) * 2048);                     \
        if ((MH) == 0) {                                                           \
            _Pragma("unroll")                                                      \
            for (int ni = 0; ni < 4; ++ni)                                         \
                bf[ni] = *(const bf16x8*)(Bb + (bswz ^ ((KH) * 64)) + ni * 2048);  \
        }                                                                          \
        STAGE_STMT;                                                                \
        __builtin_amdgcn_s_setprio(1);                                             \
        _Pragma("unroll")                                                          \
        for (int mi = 0; mi < 4; ++mi)                                             \
            _Pragma("unroll")                                                      \
            for (int ni = 0; ni < 4; ++ni)                                         \
                acc[(MH) * 4 + mi][ni] = __builtin_amdgcn_mfma_f32_16x16x32_bf16(  \
                    af[mi], bf[ni], acc[(MH) * 4 + mi][ni], 0, 0, 0);              \
        __builtin_amdgcn_s_setprio(0);                                             \
        VM_STMT;                                                                   \
        __builtin_amdgcn_s_barrier();                                              \
    }

__global__ __launch_bounds__(512, 2)
void k_gemm_max8(const bf16_t* __restrict__ q, const bf16_t* __restrict__ kp,
                 float* __restrict__ Mout) {
    __shared__ __align__(16) bf16_t lds[65536];   // 128 KiB
    char* ldsb = (char*)lds;
    int bid = blockIdx.x;           // 256 blocks
    int img = bid & 7;              // XCD-local key image
    int qp = bid >> 3;              // 0..31
    int i0 = qp * 256;
    const bf16_t* kb = kp + (size_t)img * HW_ * C_;
    int tid = threadIdx.x;
    int lane = tid & 63, w = tid >> 6;
    int wr = w >> 2, wc = w & 3;    // 2 x 4 wave grid
    int lr = lane & 15, lg = lane >> 4;
    int kswz = (lg ^ (lr & 7)) << 4;
    int aswz = lr * 128 + kswz;
    int bswz = ((wc & 1) * 64 + lr) * 128 + kswz;

    int srow = tid >> 3;
    int sk = (((tid & 7) ^ ((tid >> 3) & 7))) << 3;
    size_t srcA = (size_t)(i0 + srow) * 512 + sk;
    size_t srcB = (size_t)srow * 512 + sk;
    int ldw = (tid >> 6) * 1024;    // wave-uniform LDS byte base

    f32x4 acc[8][4];
    bf16x8 af[4], bf[4];
    float rm[8][4];
#pragma unroll
    for (int mi = 0; mi < 8; ++mi)
#pragma unroll
        for (int ni = 0; ni < 4; ++ni)
#pragma unroll
            for (int r = 0; r < 4; ++r) acc[mi][ni][r] = 0.f;
#pragma unroll
    for (int mi = 0; mi < 8; ++mi)
#pragma unroll
        for (int r = 0; r < 4; ++r) rm[mi][r] = -3.4e38f;

    // prologue: t0 all 4 regions (d0), t1 B0 (d1)
    STAGE_B(0, 0, 0) STAGE_A(0, 0, 0) STAGE_B(1, 0, 0) STAGE_A(1, 0, 0)
    STAGE_B(0, 1, 1)
    asm volatile("s_waitcnt vmcnt(2)" ::: "memory");
    __builtin_amdgcn_s_barrier();

    for (int i = 0; i < 16; ++i) {
        int tb = 2 * i + 1, tc = 2 * i + 2, td = 2 * i + 3;
        bool s = (i < 15);
        PHASE(0, 0, 0, { STAGE_A(0, 1, tb) }, {})
        PHASE(0, 0, 1, { STAGE_B(1, 1, tb) }, {})
        PHASE(0, 1, 0, { STAGE_A(1, 1, tb) }, {})
        PHASE(0, 1, 1, { if (s) { STAGE_B(0, 0, tc) } },
              { if (s) { asm volatile("s_waitcnt vmcnt(2)" ::: "memory"); }
                else   { asm volatile("s_waitcnt vmcnt(0)" ::: "memory"); } })
        PHASE(1, 0, 0, { if (s) { STAGE_A(0, 0, tc) } }, {})
        PHASE(1, 0, 1, { if (s) { STAGE_B(1, 0, tc) } }, {})
        PHASE(1, 1, 0, { if (s) { STAGE_A(1, 0, tc) } }, {})
        PHASE(1, 1, 1, { if (s) { STAGE_B(0, 1, td) } },
              { if (s) { asm volatile("s_waitcnt vmcnt(2)" ::: "memory"); } })
        if ((i & 3) == 3) {   // n-chunk complete: fold acc into rm, reset acc
#pragma unroll
            for (int mi = 0; mi < 8; ++mi)
#pragma unroll
                for (int r = 0; r < 4; ++r) {
                    float v = fmaxf(fmaxf(acc[mi][0][r], acc[mi][1][r]),
                                    fmaxf(acc[mi][2][r], acc[mi][3][r]));
                    rm[mi][r] = fmaxf(rm[mi][r], v);
#pragma unroll
                    for (int ni = 0; ni < 4; ++ni) acc[mi][ni][r] = 0.f;
                }
        }
    }

    // epilogue: reduce across 16 col-lanes, then across the 4 wc waves
#pragma unroll
    for (int mi = 0; mi < 8; ++mi)
#pragma unroll
        for (int r = 0; r < 4; ++r) {
            float v = rm[mi][r];
#pragma unroll
            for (int off = 1; off < 16; off <<= 1) v = fmaxf(v, __shfl_xor(v, off));
            rm[mi][r] = v;
        }
    float* sm = (float*)lds;
    if (lr == 0) {
#pragma unroll
        for (int mi = 0; mi < 8; ++mi)
#pragma unroll
            for (int r = 0; r < 4; ++r)
                sm[wc * 256 + wr * 128 + mi * 16 + lg * 4 + r] = rm[mi][r];
    }
    __syncthreads();
    if (tid < 256) {
        float v = fmaxf(fmaxf(sm[tid], sm[256 + tid]),
                        fmaxf(sm[512 + tid], sm[768 + tid]));
        Mout[(size_t)(i0 + tid) * 8 + img] = v;
    }
}

// ---- K4: mean over key images, scale, softmax per query image ----
__global__ void k_softmax(const float* __restrict__ Mout, float* __restrict__ wsm) {
    int b = blockIdx.x;
    int t = threadIdx.x;
    __shared__ float red[16];
    const float scale = 0.044194173824159216f;  // 1/sqrt(512)
    float s[4];
#pragma unroll
    for (int i = 0; i < 4; ++i) {
        int p = t + i * 256;
        const float4* row = (const float4*)&Mout[(size_t)(b * 1024 + p) * 8];
        float4 r0 = row[0], r1 = row[1];
        float acc = (r0.x + r0.y + r0.z + r0.w) + (r1.x + r1.y + r1.z + r1.w);
        s[i] = acc * (scale / 8.0f);
    }
    float m = fmaxf(fmaxf(s[0], s[1]), fmaxf(s[2], s[3]));
#pragma unroll
    for (int off = 1; off < 64; off <<= 1) m = fmaxf(m, __shfl_xor(m, off));
    if ((t & 63) == 0) red[t >> 6] = m;
    __syncthreads();
    float m4 = fmaxf(fmaxf(red[0], red[1]), fmaxf(red[2], red[3]));
    float e[4], sum = 0.f;
#pragma unroll
    for (int i = 0; i < 4; ++i) { e[i] = __expf(s[i] - m4); sum += e[i]; }
#pragma unroll
    for (int off = 1; off < 64; off <<= 1) sum += __shfl_xor(sum, off);
    if ((t & 63) == 0) red[8 + (t >> 6)] = sum;
    __syncthreads();
    float tot = red[8] + red[9] + red[10] + red[11];
    float inv = 1.0f / tot;
#pragma unroll
    for (int i = 0; i < 4; ++i) wsm[b * 1024 + t + i * 256] = e[i] * inv;
}

// ---- K5: y[c] = mean_{b,p} x[b,c,p] * w[b,p]  (float4 loads) ----
__global__ void k_reduce_y(const float* __restrict__ x, const float* __restrict__ wsm,
                           float* __restrict__ y) {
    int c = blockIdx.x;
    int t = threadIdx.x;
    float acc = 0.f;
#pragma unroll
    for (int b = 0; b < 8; ++b) {
        float4 xv = ((const float4*)(x + ((size_t)(b * C_ + c)) * HW_))[t];
        float4 wv = ((const float4*)(wsm + b * HW_))[t];
        acc += xv.x * wv.x + xv.y * wv.y + xv.z * wv.z + xv.w * wv.w;
    }
#pragma unroll
    for (int off = 1; off < 64; off <<= 1) acc += __shfl_xor(acc, off);
    __shared__ float red[4];
    if ((t & 63) == 0) red[t >> 6] = acc;
    __syncthreads();
    if (t == 0) y[c] = (red[0] + red[1] + red[2] + red[3]) * (1.0f / 8192.0f);
}

// ---- K6: out = x * proto[c], proto computed in-block (fused k_proto) ----
__global__ void k_final(const float* __restrict__ x, const float* __restrict__ W6,
                        const float* __restrict__ b6, const float* __restrict__ y,
                        float* __restrict__ out) {
    int bid = blockIdx.x;           // 4096 = B_*C_
    int t = threadIdx.x;
    int c = bid & 511;
    float a = W6[(size_t)c * C_ + t] * y[t] +
              W6[(size_t)c * C_ + t + 256] * y[t + 256];
#pragma unroll
    for (int off = 1; off < 64; off <<= 1) a += __shfl_xor(a, off);
    __shared__ float red[4];
    if ((t & 63) == 0) red[t >> 6] = a;
    __syncthreads();
    float p = red[0] + red[1] + red[2] + red[3] + b6[c];
    int idx = bid * 256 + t;
    float4 v = ((const float4*)x)[idx];
    v.x *= p; v.y *= p; v.z *= p; v.w *= p;
    ((float4*)out)[idx] = v;
}

extern "C" void kernel_launch(void* const* d_in, const int* in_sizes, int n_in,
                              void* d_out, int out_size, void* d_ws, size_t ws_size,
                              hipStream_t stream) {
    const float* x  = (const float*)d_in[0];
    const float* Wq = (const float*)d_in[1];
    const float* bq = (const float*)d_in[2];
    const float* Wk = (const float*)d_in[3];
    const float* bk = (const float*)d_in[4];
    const float* W6 = (const float*)d_in[5];
    const float* b6 = (const float*)d_in[6];
    float* out = (float*)d_out;

    char* ws = (char*)d_ws;
    bf16_t* xT    = (bf16_t*)(ws);                 // 8.4 MB (dead after k_gemm_qk)
    float*  Mout  = (float*)(ws);                  // 8192*8*4 = 256 KB, aliases xT
    bf16_t* wqb   = (bf16_t*)(ws + 8388608);
    bf16_t* wkb   = (bf16_t*)(ws + 8912896);
    bf16_t* qb    = (bf16_t*)(ws + 9437184);
    bf16_t* kb    = (bf16_t*)(ws + 17825792);
    float*  wsm   = (float*)(ws + 26476544);
    float*  yv    = (float*)(ws + 26509312);

    hipLaunchKernelGGL(k_transpose, dim3(16, 8, 8), dim3(256), 0, stream,
                       x, xT, Wq, Wk, wqb, wkb);
    hipLaunchKernelGGL(k_gemm_qk, dim3(512), dim3(256), 0, stream,
                       xT, wqb, wkb, bq, bk, qb, kb);
    hipLaunchKernelGGL(k_gemm_max8, dim3(256), dim3(512), 0, stream, qb, kb, Mout);
    hipLaunchKernelGGL(k_softmax, dim3(8), dim3(256), 0, stream, Mout, wsm);
    hipLaunchKernelGGL(k_reduce_y, dim3(512), dim3(256), 0, stream, x, wsm, yv);
    hipLaunchKernelGGL(k_final, dim3(4096), dim3(256), 0, stream, x, W6, b6, yv, out);
}